// Round 5
// baseline (444.614 us; speedup 1.0000x reference)
//
#include <hip/hip_runtime.h>
#include <math.h>

// ---------------------------------------------------------------------------
// GAT node classifier: 2x GATConv(H=2, concat=False/head-mean) + Linear.
//   1. bucket edges by graph (packed ushort: dst_loc<<8 | src_loc)
//   2. h = X @ W (fp32, 64 rows/block, 4x8 reg tile) + fused attention logits
//   3. agg: ONE BLOCK (1024 thr) PER GRAPH; LDS: bf16 h tile + local CSR built
//      from the bucket; segment softmax + weighted gather entirely from LDS.
//   4. preds = B @ Wc + bc ; y passthrough
// ---------------------------------------------------------------------------

#define NPG 100    // nodes per graph (fixed by problem)
#define CAP 2560   // bucket capacity per graph (mean 1700, +21 sigma)
#define HPAD 136   // padded bf16 row stride (272 B: 8B-aligned, bank-shifted)

__device__ __forceinline__ float lrelu(float x) { return x > 0.f ? x : 0.2f * x; }

__device__ __forceinline__ unsigned short f2bf(float f) {
    unsigned int u = __float_as_uint(f);
    return (unsigned short)((u + 0x7FFF + ((u >> 16) & 1)) >> 16);  // RNE
}
__device__ __forceinline__ float bf2f(unsigned short b) {
    return __uint_as_float((unsigned int)b << 16);
}

__global__ void bucket_kernel(const int* __restrict__ src, const int* __restrict__ dst,
                              int* gcnt, unsigned short* __restrict__ bucket, int e) {
    int i = blockIdx.x * 256 + threadIdx.x;
    if (i < e) {
        int d = dst[i];
        int s = src[i];
        int g = d / NPG;
        int dloc = d - g * NPG;
        int sloc = s - g * NPG;
        int pos = atomicAdd(&gcnt[g], 1);
        if (pos < CAP)
            bucket[(size_t)g * CAP + pos] = (unsigned short)((dloc << 8) | sloc);
    }
}

// X [n,K] @ W [K,128] -> H [n,128], fused attention logits.
template <int K>
__global__ __launch_bounds__(256) void gemm_nodes(const float* __restrict__ X,
                                                  const float* __restrict__ W,
                                                  const float* __restrict__ a_src,
                                                  const float* __restrict__ a_dst,
                                                  float* __restrict__ H,
                                                  float* __restrict__ als,
                                                  float* __restrict__ ald, int n) {
    constexpr int KC = 32;
    __shared__ float sX[64][KC + 1];
    __shared__ float sW[KC][132];
    int tid = threadIdx.x;
    int row0 = blockIdx.x * 64;
    int rg = tid >> 4;
    int cg = tid & 15;
    int r0 = rg * 4;
    int c0 = cg * 8;
    float acc[4][8];
#pragma unroll
    for (int i = 0; i < 4; ++i)
#pragma unroll
        for (int j = 0; j < 8; ++j) acc[i][j] = 0.f;

    for (int kc = 0; kc < K; kc += KC) {
        __syncthreads();
#pragma unroll
        for (int it = 0; it < 2; ++it) {
            int idx = tid + it * 256;
            int r = idx >> 3;
            int k4 = (idx & 7) * 4;
            int gr = row0 + r;
            float4 v = (gr < n) ? *reinterpret_cast<const float4*>(&X[(size_t)gr * K + kc + k4])
                                : make_float4(0.f, 0.f, 0.f, 0.f);
            sX[r][k4 + 0] = v.x; sX[r][k4 + 1] = v.y;
            sX[r][k4 + 2] = v.z; sX[r][k4 + 3] = v.w;
        }
#pragma unroll
        for (int it = 0; it < 4; ++it) {
            int idx = tid + it * 256;
            int kk = idx >> 5;
            int c4 = (idx & 31) * 4;
            *reinterpret_cast<float4*>(&sW[kk][c4]) =
                *reinterpret_cast<const float4*>(&W[(size_t)(kc + kk) * 128 + c4]);
        }
        __syncthreads();
#pragma unroll
        for (int k = 0; k < KC; ++k) {
            float x0 = sX[r0 + 0][k];
            float x1 = sX[r0 + 1][k];
            float x2 = sX[r0 + 2][k];
            float x3 = sX[r0 + 3][k];
            float4 w0 = *reinterpret_cast<const float4*>(&sW[k][c0]);
            float4 w1 = *reinterpret_cast<const float4*>(&sW[k][c0 + 4]);
            acc[0][0] += x0 * w0.x; acc[0][1] += x0 * w0.y; acc[0][2] += x0 * w0.z; acc[0][3] += x0 * w0.w;
            acc[0][4] += x0 * w1.x; acc[0][5] += x0 * w1.y; acc[0][6] += x0 * w1.z; acc[0][7] += x0 * w1.w;
            acc[1][0] += x1 * w0.x; acc[1][1] += x1 * w0.y; acc[1][2] += x1 * w0.z; acc[1][3] += x1 * w0.w;
            acc[1][4] += x1 * w1.x; acc[1][5] += x1 * w1.y; acc[1][6] += x1 * w1.z; acc[1][7] += x1 * w1.w;
            acc[2][0] += x2 * w0.x; acc[2][1] += x2 * w0.y; acc[2][2] += x2 * w0.z; acc[2][3] += x2 * w0.w;
            acc[2][4] += x2 * w1.x; acc[2][5] += x2 * w1.y; acc[2][6] += x2 * w1.z; acc[2][7] += x2 * w1.w;
            acc[3][0] += x3 * w0.x; acc[3][1] += x3 * w0.y; acc[3][2] += x3 * w0.z; acc[3][3] += x3 * w0.w;
            acc[3][4] += x3 * w1.x; acc[3][5] += x3 * w1.y; acc[3][6] += x3 * w1.z; acc[3][7] += x3 * w1.w;
        }
    }

#pragma unroll
    for (int i = 0; i < 4; ++i) {
        int gr = row0 + r0 + i;
        if (gr < n) {
            float4* o = reinterpret_cast<float4*>(&H[(size_t)gr * 128 + c0]);
            o[0] = make_float4(acc[i][0], acc[i][1], acc[i][2], acc[i][3]);
            o[1] = make_float4(acc[i][4], acc[i][5], acc[i][6], acc[i][7]);
        }
    }

    float ps[4], pd[4];
#pragma unroll
    for (int i = 0; i < 4; ++i) {
        float s = 0.f, d = 0.f;
#pragma unroll
        for (int j = 0; j < 8; ++j) {
            float av = acc[i][j];
            s += av * a_src[c0 + j];
            d += av * a_dst[c0 + j];
        }
        ps[i] = s; pd[i] = d;
    }
#pragma unroll
    for (int off = 1; off <= 4; off <<= 1) {
#pragma unroll
        for (int i = 0; i < 4; ++i) {
            ps[i] += __shfl_xor(ps[i], off);
            pd[i] += __shfl_xor(pd[i], off);
        }
    }
    if ((cg & 7) == 0) {
        int head = cg >> 3;
#pragma unroll
        for (int i = 0; i < 4; ++i) {
            int gr = row0 + r0 + i;
            if (gr < n) {
                als[gr * 2 + head] = ps[i];
                ald[gr * 2 + head] = pd[i];
            }
        }
    }
}

// One block (1024 threads = 16 waves) per graph. Stage h as bf16 in LDS,
// build local CSR from the graph bucket, then per-dst segment softmax +
// weighted gather entirely from LDS. 2 edges/iter in the gather.
template <bool RELU>
__global__ __launch_bounds__(1024) void agg_graph(const float* __restrict__ Hf,
                                                  const float* __restrict__ als,
                                                  const float* __restrict__ ald,
                                                  const int* __restrict__ gcnt,
                                                  const unsigned short* __restrict__ bucket,
                                                  const float* __restrict__ bias,
                                                  float* __restrict__ out, int n) {
    __shared__ unsigned short sH[NPG][HPAD];   // bf16 h tile, 27.2 KB
    __shared__ float sAs[NPG * 2];
    __shared__ float sAd[NPG * 2];
    __shared__ int sdeg[NPG];
    __shared__ int srow[NPG + 1];
    __shared__ int scur[NPG];
    __shared__ unsigned char sadj[CAP];
    __shared__ int swtot;

    int g = blockIdx.x;
    int gbase = g * NPG;
    int tid = threadIdx.x;
    int lane = tid & 63, wave = tid >> 6;
    int cnt = min(gcnt[g], CAP);

    if (tid < NPG) sdeg[tid] = 0;
    // stage h -> bf16 (100 rows x 32 float4)
    for (int i = tid; i < NPG * 32; i += 1024) {
        int r = i >> 5, c4 = (i & 31) * 4;
        float4 v = *reinterpret_cast<const float4*>(&Hf[(size_t)(gbase + r) * 128 + c4]);
        ushort4 b;
        b.x = f2bf(v.x); b.y = f2bf(v.y); b.z = f2bf(v.z); b.w = f2bf(v.w);
        *reinterpret_cast<ushort4*>(&sH[r][c4]) = b;
    }
    for (int i = tid; i < NPG * 2; i += 1024) {
        sAs[i] = als[gbase * 2 + i];
        sAd[i] = ald[gbase * 2 + i];
    }
    __syncthreads();

    // local degree count
    for (int i = tid; i < cnt; i += 1024)
        atomicAdd(&sdeg[bucket[(size_t)g * CAP + i] >> 8], 1);
    __syncthreads();

    // exclusive scan over 100 degrees (waves 0-1 via shfl)
    {
        int v = (tid < NPG) ? sdeg[tid] : 0;
        int x = v;
        if (tid < 128) {
            for (int off = 1; off < 64; off <<= 1) {
                int t = __shfl_up(x, off);
                if (lane >= off) x += t;
            }
        }
        if (tid == 63) swtot = x;
        __syncthreads();
        if (tid >= 64 && tid < NPG) x += swtot;
        if (tid < NPG) {
            srow[tid + 1] = x;
            scur[tid] = x - v;
        }
        if (tid == 0) srow[0] = 0;
    }
    __syncthreads();

    // scatter edges into local CSR
    for (int i = tid; i < cnt; i += 1024) {
        unsigned short v = bucket[(size_t)g * CAP + i];
        int pos = atomicAdd(&scur[v >> 8], 1);
        sadj[pos] = (unsigned char)(v & 255);
    }
    __syncthreads();

    int q = lane & 31;      // channel group: sH cols 4q..4q+3
    int half = lane >> 5;   // edge parity
    float4 bv = *reinterpret_cast<const float4*>(&bias[(q & 15) * 4]);

    for (int d = wave; d < NPG; d += 16) {
        int node = gbase + d;
        int beg = srow[d], end = srow[d + 1];
        float ad0 = sAd[d * 2], ad1 = sAd[d * 2 + 1];

        // chunk-0 logits in registers
        int j0 = beg + lane;
        int s0 = 0;
        float ea0 = -INFINITY, ea1 = -INFINITY;
        if (j0 < end) {
            s0 = sadj[j0];
            ea0 = lrelu(sAs[s0 * 2] + ad0);
            ea1 = lrelu(sAs[s0 * 2 + 1] + ad1);
        }
        float m0 = ea0, m1 = ea1;
        for (int c = beg + 64; c < end; c += 64) {   // deg > 64: essentially never
            int j = c + lane;
            if (j < end) {
                int s = sadj[j];
                m0 = fmaxf(m0, lrelu(sAs[s * 2] + ad0));
                m1 = fmaxf(m1, lrelu(sAs[s * 2 + 1] + ad1));
            }
        }
        for (int off = 32; off; off >>= 1) {
            m0 = fmaxf(m0, __shfl_xor(m0, off));
            m1 = fmaxf(m1, __shfl_xor(m1, off));
        }

        float p0 = __expf(ea0 - m0);   // inactive lanes: exp(-inf) = 0
        float p1 = __expf(ea1 - m1);
        float z0 = p0, z1 = p1;

        float acc[4] = {0.f, 0.f, 0.f, 0.f};
        int cnt0 = min(64, end - beg);
        for (int t = 0; t < cnt0; t += 2) {
            int tl = t + half;
            int sj = __shfl(s0, tl);
            float pj0 = __shfl(p0, tl);
            float pj1 = __shfl(p1, tl);
            float psel = (q < 16) ? pj0 : pj1;   // 0 when tl >= active count
            ushort4 hb = *reinterpret_cast<const ushort4*>(&sH[sj][q * 4]);
            acc[0] += psel * bf2f(hb.x); acc[1] += psel * bf2f(hb.y);
            acc[2] += psel * bf2f(hb.z); acc[3] += psel * bf2f(hb.w);
        }
        for (int c = beg + 64; c < end; c += 64) {   // rare tail
            int j = c + lane;
            int s = 0;
            float q0 = 0.f, q1 = 0.f;
            if (j < end) {
                s = sadj[j];
                q0 = __expf(lrelu(sAs[s * 2] + ad0) - m0);
                q1 = __expf(lrelu(sAs[s * 2 + 1] + ad1) - m1);
            }
            z0 += q0; z1 += q1;
            int cc = min(64, end - c);
            for (int t = 0; t < cc; t += 2) {
                int tl = t + half;
                int sj = __shfl(s, tl);
                float pj0 = __shfl(q0, tl);
                float pj1 = __shfl(q1, tl);
                float psel = (q < 16) ? pj0 : pj1;
                ushort4 hb = *reinterpret_cast<const ushort4*>(&sH[sj][q * 4]);
                acc[0] += psel * bf2f(hb.x); acc[1] += psel * bf2f(hb.y);
                acc[2] += psel * bf2f(hb.z); acc[3] += psel * bf2f(hb.w);
            }
        }

        for (int off = 32; off; off >>= 1) {
            z0 += __shfl_xor(z0, off);
            z1 += __shfl_xor(z1, off);
        }
        float zsel = (q < 16) ? z0 : z1;
#pragma unroll
        for (int c = 0; c < 4; ++c) {
            acc[c] += __shfl_xor(acc[c], 32);   // merge edge parities
            acc[c] /= zsel;                     // per-head normalize
            acc[c] += __shfl_xor(acc[c], 16);   // head0 + head1
        }
        if (lane < 16) {
            float4 r;
            r.x = 0.5f * acc[0] + bv.x;
            r.y = 0.5f * acc[1] + bv.y;
            r.z = 0.5f * acc[2] + bv.z;
            r.w = 0.5f * acc[3] + bv.w;
            if (RELU) {
                r.x = fmaxf(r.x, 0.f); r.y = fmaxf(r.y, 0.f);
                r.z = fmaxf(r.z, 0.f); r.w = fmaxf(r.w, 0.f);
            }
            *reinterpret_cast<float4*>(&out[(size_t)node * 64 + lane * 4]) = r;
        }
    }
}

// preds = Hf [n,64] @ Wc [64,10] + bc; one thread per node.
__global__ __launch_bounds__(256) void cls_kernel(const float* __restrict__ Hf,
                                                  const float* __restrict__ Wc,
                                                  const float* __restrict__ bc,
                                                  float* __restrict__ out, int n) {
    __shared__ float sW[640];
    __shared__ float sb[10];
    int tid = threadIdx.x;
    for (int i = tid; i < 640; i += 256) sW[i] = Wc[i];
    if (tid < 10) sb[tid] = bc[tid];
    __syncthreads();
    int node = blockIdx.x * 256 + tid;
    if (node >= n) return;
    float acc[10];
#pragma unroll
    for (int j = 0; j < 10; ++j) acc[j] = sb[j];
    for (int k = 0; k < 64; k += 4) {
        float4 h4 = *reinterpret_cast<const float4*>(&Hf[(size_t)node * 64 + k]);
#pragma unroll
        for (int j = 0; j < 10; ++j) {
            acc[j] += h4.x * sW[(k + 0) * 10 + j];
            acc[j] += h4.y * sW[(k + 1) * 10 + j];
            acc[j] += h4.z * sW[(k + 2) * 10 + j];
            acc[j] += h4.w * sW[(k + 3) * 10 + j];
        }
    }
#pragma unroll
    for (int j = 0; j < 10; ++j) out[(size_t)node * 10 + j] = acc[j];
}

__global__ void ycopy_kernel(const int* __restrict__ y, float* __restrict__ out, int n) {
    int i = blockIdx.x * 256 + threadIdx.x;
    if (i < n) out[i] = (float)y[i];
}

extern "C" void kernel_launch(void* const* d_in, const int* in_sizes, int n_in,
                              void* d_out, int out_size, void* d_ws, size_t ws_size,
                              hipStream_t stream) {
    const float* x   = (const float*)d_in[0];
    const int*   ei  = (const int*)d_in[1];
    const int*   y   = (const int*)d_in[3];
    const float* W1  = (const float*)d_in[4];
    const float* as1 = (const float*)d_in[5];
    const float* ad1 = (const float*)d_in[6];
    const float* b1  = (const float*)d_in[7];
    const float* W2  = (const float*)d_in[8];
    const float* as2 = (const float*)d_in[9];
    const float* ad2 = (const float*)d_in[10];
    const float* b2  = (const float*)d_in[11];
    const float* Wc  = (const float*)d_in[12];
    const float* bc  = (const float*)d_in[13];

    int n = in_sizes[0] / 128;   // 50000
    int e = in_sizes[1] / 2;     // 850000
    int G = n / NPG;             // 500 graphs
    const int* src = ei;
    const int* dst = ei + e;

    char* ws = (char*)d_ws;
    size_t off = 0;
    auto alloc = [&](size_t bytes) -> void* {
        void* p = ws + off;
        off = (off + bytes + 255) & ~size_t(255);
        return p;
    };
    float* A    = (float*)alloc((size_t)n * 128 * 4);
    float* B    = (float*)alloc((size_t)n * 64 * 4);
    float* als  = (float*)alloc((size_t)n * 2 * 4);
    float* ald  = (float*)alloc((size_t)n * 2 * 4);
    int*   gcnt = (int*)alloc((size_t)G * 4);
    unsigned short* bucket = (unsigned short*)alloc((size_t)G * CAP * 2);

    float* preds = (float*)d_out;
    float* yout  = preds + (size_t)n * 10;

    int eb = (e + 255) / 256;
    int nb64 = (n + 63) / 64;
    int nb256 = (n + 255) / 256;

    // bucket edges by graph (rebuilt every call: no cross-call state)
    hipMemsetAsync(gcnt, 0, (size_t)G * 4, stream);
    bucket_kernel<<<eb, 256, 0, stream>>>(src, dst, gcnt, bucket, e);

    // layer 1
    gemm_nodes<128><<<nb64, 256, 0, stream>>>(x, W1, as1, ad1, A, als, ald, n);
    agg_graph<true><<<G, 1024, 0, stream>>>(A, als, ald, gcnt, bucket, b1, B, n);

    // layer 2
    gemm_nodes<64><<<nb64, 256, 0, stream>>>(B, W2, as2, ad2, A, als, ald, n);
    agg_graph<false><<<G, 1024, 0, stream>>>(A, als, ald, gcnt, bucket, b2, B, n);

    // classifier + y passthrough
    cls_kernel<<<nb256, 256, 0, stream>>>(B, Wc, bc, preds, n);
    ycopy_kernel<<<nb256, 256, 0, stream>>>(y, yout, n);
}

// Round 6
// 171.952 us; speedup vs baseline: 2.5857x; 2.5857x over previous
//
#include <hip/hip_runtime.h>
#include <math.h>

// ---------------------------------------------------------------------------
// GAT node classifier: 2x GATConv(H=2, concat=False/head-mean) + Linear.
//   1. bucket edges by graph, two-level: LDS histogram + one global
//      atomicAdd per (block,graph) range reservation, then LDS->global scatter
//      (packed ushort: dst_loc<<8 | src_loc)
//   2. h = X @ W (fp32, 64 rows/block, 4x8 reg tile) + fused attention logits
//   3. agg: ONE BLOCK (1024 thr) PER GRAPH; LDS: bf16 h tile + local CSR built
//      from the bucket; segment softmax + weighted gather entirely from LDS.
//   4. preds = B @ Wc + bc ; y passthrough
// ---------------------------------------------------------------------------

#define NPG 100    // nodes per graph (fixed by problem)
#define CAP 2560   // bucket capacity per graph (mean 1700, +21 sigma)
#define HPAD 136   // padded bf16 row stride (272 B: 8B-aligned, bank-shifted)
#define EPB 4096   // edges per bucket-build block

__device__ __forceinline__ float lrelu(float x) { return x > 0.f ? x : 0.2f * x; }

__device__ __forceinline__ unsigned short f2bf(float f) {
    unsigned int u = __float_as_uint(f);
    return (unsigned short)((u + 0x7FFF + ((u >> 16) & 1)) >> 16);  // RNE
}
__device__ __forceinline__ float bf2f(unsigned short b) {
    return __uint_as_float((unsigned int)b << 16);
}

// Two-level bucketing: per-block LDS histogram over graphs, one global
// reservation per (block, graph), then scatter staged edges to the reserved
// contiguous sub-ranges.
__global__ __launch_bounds__(1024) void bucket2_kernel(const int* __restrict__ src,
                                                       const int* __restrict__ dst,
                                                       int* gcnt,
                                                       unsigned short* __restrict__ bucket,
                                                       int e) {
    __shared__ int hist[512];
    __shared__ int base[512];
    __shared__ unsigned int staged[EPB];
    int tid = threadIdx.x;
    int e0 = blockIdx.x * EPB;
    int cnt = min(EPB, e - e0);

    for (int i = tid; i < 512; i += 1024) hist[i] = 0;
    __syncthreads();

    for (int i = tid; i < cnt; i += 1024) {
        int d = dst[e0 + i];
        int s = src[e0 + i];
        int g = d / NPG;
        int dloc = d - g * NPG;
        int sloc = s - g * NPG;
        staged[i] = ((unsigned)g << 16) | ((unsigned)dloc << 8) | (unsigned)sloc;
        atomicAdd(&hist[g], 1);
    }
    __syncthreads();

    if (tid < 512) {
        int h = hist[tid];
        base[tid] = h ? atomicAdd(&gcnt[tid], h) : 0;
        hist[tid] = 0;   // reuse as local cursor
    }
    __syncthreads();

    for (int i = tid; i < cnt; i += 1024) {
        unsigned v = staged[i];
        int g = v >> 16;
        int pos = base[g] + atomicAdd(&hist[g], 1);
        if (pos < CAP)
            bucket[(size_t)g * CAP + pos] = (unsigned short)(v & 0xFFFFu);
    }
}

// X [n,K] @ W [K,128] -> H [n,128], fused attention logits.
template <int K>
__global__ __launch_bounds__(256) void gemm_nodes(const float* __restrict__ X,
                                                  const float* __restrict__ W,
                                                  const float* __restrict__ a_src,
                                                  const float* __restrict__ a_dst,
                                                  float* __restrict__ H,
                                                  float* __restrict__ als,
                                                  float* __restrict__ ald, int n) {
    constexpr int KC = 32;
    __shared__ float sX[64][KC + 1];
    __shared__ float sW[KC][132];
    int tid = threadIdx.x;
    int row0 = blockIdx.x * 64;
    int rg = tid >> 4;
    int cg = tid & 15;
    int r0 = rg * 4;
    int c0 = cg * 8;
    float acc[4][8];
#pragma unroll
    for (int i = 0; i < 4; ++i)
#pragma unroll
        for (int j = 0; j < 8; ++j) acc[i][j] = 0.f;

    for (int kc = 0; kc < K; kc += KC) {
        __syncthreads();
#pragma unroll
        for (int it = 0; it < 2; ++it) {
            int idx = tid + it * 256;
            int r = idx >> 3;
            int k4 = (idx & 7) * 4;
            int gr = row0 + r;
            float4 v = (gr < n) ? *reinterpret_cast<const float4*>(&X[(size_t)gr * K + kc + k4])
                                : make_float4(0.f, 0.f, 0.f, 0.f);
            sX[r][k4 + 0] = v.x; sX[r][k4 + 1] = v.y;
            sX[r][k4 + 2] = v.z; sX[r][k4 + 3] = v.w;
        }
#pragma unroll
        for (int it = 0; it < 4; ++it) {
            int idx = tid + it * 256;
            int kk = idx >> 5;
            int c4 = (idx & 31) * 4;
            *reinterpret_cast<float4*>(&sW[kk][c4]) =
                *reinterpret_cast<const float4*>(&W[(size_t)(kc + kk) * 128 + c4]);
        }
        __syncthreads();
#pragma unroll
        for (int k = 0; k < KC; ++k) {
            float x0 = sX[r0 + 0][k];
            float x1 = sX[r0 + 1][k];
            float x2 = sX[r0 + 2][k];
            float x3 = sX[r0 + 3][k];
            float4 w0 = *reinterpret_cast<const float4*>(&sW[k][c0]);
            float4 w1 = *reinterpret_cast<const float4*>(&sW[k][c0 + 4]);
            acc[0][0] += x0 * w0.x; acc[0][1] += x0 * w0.y; acc[0][2] += x0 * w0.z; acc[0][3] += x0 * w0.w;
            acc[0][4] += x0 * w1.x; acc[0][5] += x0 * w1.y; acc[0][6] += x0 * w1.z; acc[0][7] += x0 * w1.w;
            acc[1][0] += x1 * w0.x; acc[1][1] += x1 * w0.y; acc[1][2] += x1 * w0.z; acc[1][3] += x1 * w0.w;
            acc[1][4] += x1 * w1.x; acc[1][5] += x1 * w1.y; acc[1][6] += x1 * w1.z; acc[1][7] += x1 * w1.w;
            acc[2][0] += x2 * w0.x; acc[2][1] += x2 * w0.y; acc[2][2] += x2 * w0.z; acc[2][3] += x2 * w0.w;
            acc[2][4] += x2 * w1.x; acc[2][5] += x2 * w1.y; acc[2][6] += x2 * w1.z; acc[2][7] += x2 * w1.w;
            acc[3][0] += x3 * w0.x; acc[3][1] += x3 * w0.y; acc[3][2] += x3 * w0.z; acc[3][3] += x3 * w0.w;
            acc[3][4] += x3 * w1.x; acc[3][5] += x3 * w1.y; acc[3][6] += x3 * w1.z; acc[3][7] += x3 * w1.w;
        }
    }

#pragma unroll
    for (int i = 0; i < 4; ++i) {
        int gr = row0 + r0 + i;
        if (gr < n) {
            float4* o = reinterpret_cast<float4*>(&H[(size_t)gr * 128 + c0]);
            o[0] = make_float4(acc[i][0], acc[i][1], acc[i][2], acc[i][3]);
            o[1] = make_float4(acc[i][4], acc[i][5], acc[i][6], acc[i][7]);
        }
    }

    float ps[4], pd[4];
#pragma unroll
    for (int i = 0; i < 4; ++i) {
        float s = 0.f, d = 0.f;
#pragma unroll
        for (int j = 0; j < 8; ++j) {
            float av = acc[i][j];
            s += av * a_src[c0 + j];
            d += av * a_dst[c0 + j];
        }
        ps[i] = s; pd[i] = d;
    }
#pragma unroll
    for (int off = 1; off <= 4; off <<= 1) {
#pragma unroll
        for (int i = 0; i < 4; ++i) {
            ps[i] += __shfl_xor(ps[i], off);
            pd[i] += __shfl_xor(pd[i], off);
        }
    }
    if ((cg & 7) == 0) {
        int head = cg >> 3;
#pragma unroll
        for (int i = 0; i < 4; ++i) {
            int gr = row0 + r0 + i;
            if (gr < n) {
                als[gr * 2 + head] = ps[i];
                ald[gr * 2 + head] = pd[i];
            }
        }
    }
}

// One block (1024 threads = 16 waves) per graph. Stage h as bf16 in LDS,
// build local CSR from the graph bucket, then per-dst segment softmax +
// weighted gather entirely from LDS. 2 edges/iter in the gather.
template <bool RELU>
__global__ __launch_bounds__(1024) void agg_graph(const float* __restrict__ Hf,
                                                  const float* __restrict__ als,
                                                  const float* __restrict__ ald,
                                                  const int* __restrict__ gcnt,
                                                  const unsigned short* __restrict__ bucket,
                                                  const float* __restrict__ bias,
                                                  float* __restrict__ out, int n) {
    __shared__ unsigned short sH[NPG][HPAD];   // bf16 h tile, 27.2 KB
    __shared__ float sAs[NPG * 2];
    __shared__ float sAd[NPG * 2];
    __shared__ int sdeg[NPG];
    __shared__ int srow[NPG + 1];
    __shared__ int scur[NPG];
    __shared__ unsigned char sadj[CAP];
    __shared__ int swtot;

    int g = blockIdx.x;
    int gbase = g * NPG;
    int tid = threadIdx.x;
    int lane = tid & 63, wave = tid >> 6;
    int cnt = min(gcnt[g], CAP);

    if (tid < NPG) sdeg[tid] = 0;
    // stage h -> bf16 (100 rows x 32 float4)
    for (int i = tid; i < NPG * 32; i += 1024) {
        int r = i >> 5, c4 = (i & 31) * 4;
        float4 v = *reinterpret_cast<const float4*>(&Hf[(size_t)(gbase + r) * 128 + c4]);
        ushort4 b;
        b.x = f2bf(v.x); b.y = f2bf(v.y); b.z = f2bf(v.z); b.w = f2bf(v.w);
        *reinterpret_cast<ushort4*>(&sH[r][c4]) = b;
    }
    for (int i = tid; i < NPG * 2; i += 1024) {
        sAs[i] = als[gbase * 2 + i];
        sAd[i] = ald[gbase * 2 + i];
    }
    __syncthreads();

    // local degree count
    for (int i = tid; i < cnt; i += 1024)
        atomicAdd(&sdeg[bucket[(size_t)g * CAP + i] >> 8], 1);
    __syncthreads();

    // exclusive scan over 100 degrees (waves 0-1 via shfl)
    {
        int v = (tid < NPG) ? sdeg[tid] : 0;
        int x = v;
        if (tid < 128) {
            for (int off = 1; off < 64; off <<= 1) {
                int t = __shfl_up(x, off);
                if (lane >= off) x += t;
            }
        }
        if (tid == 63) swtot = x;
        __syncthreads();
        if (tid >= 64 && tid < NPG) x += swtot;
        if (tid < NPG) {
            srow[tid + 1] = x;
            scur[tid] = x - v;
        }
        if (tid == 0) srow[0] = 0;
    }
    __syncthreads();

    // scatter edges into local CSR
    for (int i = tid; i < cnt; i += 1024) {
        unsigned short v = bucket[(size_t)g * CAP + i];
        int pos = atomicAdd(&scur[v >> 8], 1);
        sadj[pos] = (unsigned char)(v & 255);
    }
    __syncthreads();

    int q = lane & 31;      // channel group: sH cols 4q..4q+3
    int half = lane >> 5;   // edge parity
    float4 bv = *reinterpret_cast<const float4*>(&bias[(q & 15) * 4]);

    for (int d = wave; d < NPG; d += 16) {
        int node = gbase + d;
        int beg = srow[d], end = srow[d + 1];
        float ad0 = sAd[d * 2], ad1 = sAd[d * 2 + 1];

        // chunk-0 logits in registers
        int j0 = beg + lane;
        int s0 = 0;
        float ea0 = -INFINITY, ea1 = -INFINITY;
        if (j0 < end) {
            s0 = sadj[j0];
            ea0 = lrelu(sAs[s0 * 2] + ad0);
            ea1 = lrelu(sAs[s0 * 2 + 1] + ad1);
        }
        float m0 = ea0, m1 = ea1;
        for (int c = beg + 64; c < end; c += 64) {   // deg > 64: essentially never
            int j = c + lane;
            if (j < end) {
                int s = sadj[j];
                m0 = fmaxf(m0, lrelu(sAs[s * 2] + ad0));
                m1 = fmaxf(m1, lrelu(sAs[s * 2 + 1] + ad1));
            }
        }
        for (int off = 32; off; off >>= 1) {
            m0 = fmaxf(m0, __shfl_xor(m0, off));
            m1 = fmaxf(m1, __shfl_xor(m1, off));
        }

        float p0 = __expf(ea0 - m0);   // inactive lanes: exp(-inf) = 0
        float p1 = __expf(ea1 - m1);
        float z0 = p0, z1 = p1;

        float acc[4] = {0.f, 0.f, 0.f, 0.f};
        int cnt0 = min(64, end - beg);
        for (int t = 0; t < cnt0; t += 2) {
            int tl = t + half;
            int sj = __shfl(s0, tl);
            float pj0 = __shfl(p0, tl);
            float pj1 = __shfl(p1, tl);
            float psel = (q < 16) ? pj0 : pj1;   // 0 when tl >= active count
            ushort4 hb = *reinterpret_cast<const ushort4*>(&sH[sj][q * 4]);
            acc[0] += psel * bf2f(hb.x); acc[1] += psel * bf2f(hb.y);
            acc[2] += psel * bf2f(hb.z); acc[3] += psel * bf2f(hb.w);
        }
        for (int c = beg + 64; c < end; c += 64) {   // rare tail
            int j = c + lane;
            int s = 0;
            float q0 = 0.f, q1 = 0.f;
            if (j < end) {
                s = sadj[j];
                q0 = __expf(lrelu(sAs[s * 2] + ad0) - m0);
                q1 = __expf(lrelu(sAs[s * 2 + 1] + ad1) - m1);
            }
            z0 += q0; z1 += q1;
            int cc = min(64, end - c);
            for (int t = 0; t < cc; t += 2) {
                int tl = t + half;
                int sj = __shfl(s, tl);
                float pj0 = __shfl(q0, tl);
                float pj1 = __shfl(q1, tl);
                float psel = (q < 16) ? pj0 : pj1;
                ushort4 hb = *reinterpret_cast<const ushort4*>(&sH[sj][q * 4]);
                acc[0] += psel * bf2f(hb.x); acc[1] += psel * bf2f(hb.y);
                acc[2] += psel * bf2f(hb.z); acc[3] += psel * bf2f(hb.w);
            }
        }

        for (int off = 32; off; off >>= 1) {
            z0 += __shfl_xor(z0, off);
            z1 += __shfl_xor(z1, off);
        }
        float zsel = (q < 16) ? z0 : z1;
#pragma unroll
        for (int c = 0; c < 4; ++c) {
            acc[c] += __shfl_xor(acc[c], 32);   // merge edge parities
            acc[c] /= zsel;                     // per-head normalize
            acc[c] += __shfl_xor(acc[c], 16);   // head0 + head1
        }
        if (lane < 16) {
            float4 r;
            r.x = 0.5f * acc[0] + bv.x;
            r.y = 0.5f * acc[1] + bv.y;
            r.z = 0.5f * acc[2] + bv.z;
            r.w = 0.5f * acc[3] + bv.w;
            if (RELU) {
                r.x = fmaxf(r.x, 0.f); r.y = fmaxf(r.y, 0.f);
                r.z = fmaxf(r.z, 0.f); r.w = fmaxf(r.w, 0.f);
            }
            *reinterpret_cast<float4*>(&out[(size_t)node * 64 + lane * 4]) = r;
        }
    }
}

// preds = Hf [n,64] @ Wc [64,10] + bc; one thread per node.
__global__ __launch_bounds__(256) void cls_kernel(const float* __restrict__ Hf,
                                                  const float* __restrict__ Wc,
                                                  const float* __restrict__ bc,
                                                  float* __restrict__ out, int n) {
    __shared__ float sW[640];
    __shared__ float sb[10];
    int tid = threadIdx.x;
    for (int i = tid; i < 640; i += 256) sW[i] = Wc[i];
    if (tid < 10) sb[tid] = bc[tid];
    __syncthreads();
    int node = blockIdx.x * 256 + tid;
    if (node >= n) return;
    float acc[10];
#pragma unroll
    for (int j = 0; j < 10; ++j) acc[j] = sb[j];
    for (int k = 0; k < 64; k += 4) {
        float4 h4 = *reinterpret_cast<const float4*>(&Hf[(size_t)node * 64 + k]);
#pragma unroll
        for (int j = 0; j < 10; ++j) {
            acc[j] += h4.x * sW[(k + 0) * 10 + j];
            acc[j] += h4.y * sW[(k + 1) * 10 + j];
            acc[j] += h4.z * sW[(k + 2) * 10 + j];
            acc[j] += h4.w * sW[(k + 3) * 10 + j];
        }
    }
#pragma unroll
    for (int j = 0; j < 10; ++j) out[(size_t)node * 10 + j] = acc[j];
}

__global__ void ycopy_kernel(const int* __restrict__ y, float* __restrict__ out, int n) {
    int i = blockIdx.x * 256 + threadIdx.x;
    if (i < n) out[i] = (float)y[i];
}

extern "C" void kernel_launch(void* const* d_in, const int* in_sizes, int n_in,
                              void* d_out, int out_size, void* d_ws, size_t ws_size,
                              hipStream_t stream) {
    const float* x   = (const float*)d_in[0];
    const int*   ei  = (const int*)d_in[1];
    const int*   y   = (const int*)d_in[3];
    const float* W1  = (const float*)d_in[4];
    const float* as1 = (const float*)d_in[5];
    const float* ad1 = (const float*)d_in[6];
    const float* b1  = (const float*)d_in[7];
    const float* W2  = (const float*)d_in[8];
    const float* as2 = (const float*)d_in[9];
    const float* ad2 = (const float*)d_in[10];
    const float* b2  = (const float*)d_in[11];
    const float* Wc  = (const float*)d_in[12];
    const float* bc  = (const float*)d_in[13];

    int n = in_sizes[0] / 128;   // 50000
    int e = in_sizes[1] / 2;     // 850000
    int G = n / NPG;             // 500 graphs
    const int* src = ei;
    const int* dst = ei + e;

    char* ws = (char*)d_ws;
    size_t off = 0;
    auto alloc = [&](size_t bytes) -> void* {
        void* p = ws + off;
        off = (off + bytes + 255) & ~size_t(255);
        return p;
    };
    float* A    = (float*)alloc((size_t)n * 128 * 4);
    float* B    = (float*)alloc((size_t)n * 64 * 4);
    float* als  = (float*)alloc((size_t)n * 2 * 4);
    float* ald  = (float*)alloc((size_t)n * 2 * 4);
    int*   gcnt = (int*)alloc((size_t)G * 4);
    unsigned short* bucket = (unsigned short*)alloc((size_t)G * CAP * 2);

    float* preds = (float*)d_out;
    float* yout  = preds + (size_t)n * 10;

    int nb64 = (n + 63) / 64;
    int nb256 = (n + 255) / 256;
    int bb = (e + EPB - 1) / EPB;

    // bucket edges by graph (rebuilt every call: no cross-call state)
    hipMemsetAsync(gcnt, 0, (size_t)G * 4, stream);
    bucket2_kernel<<<bb, 1024, 0, stream>>>(src, dst, gcnt, bucket, e);

    // layer 1
    gemm_nodes<128><<<nb64, 256, 0, stream>>>(x, W1, as1, ad1, A, als, ald, n);
    agg_graph<true><<<G, 1024, 0, stream>>>(A, als, ald, gcnt, bucket, b1, B, n);

    // layer 2
    gemm_nodes<64><<<nb64, 256, 0, stream>>>(B, W2, as2, ad2, A, als, ald, n);
    agg_graph<false><<<G, 1024, 0, stream>>>(A, als, ald, gcnt, bucket, b2, B, n);

    // classifier + y passthrough
    cls_kernel<<<nb256, 256, 0, stream>>>(B, Wc, bc, preds, n);
    ycopy_kernel<<<nb256, 256, 0, stream>>>(y, yout, n);
}

// Round 8
// 147.622 us; speedup vs baseline: 3.0118x; 1.1648x over previous
//
#include <hip/hip_runtime.h>
#include <math.h>

// ---------------------------------------------------------------------------
// GAT node classifier: 2x GATConv(H=2, concat=False/head-mean) + Linear.
//   1. bucket edges by graph (two-level LDS-histogram scatter, packed ushort)
//   2. h = X @ W (fp32, 64 rows/block, 4x8 reg tile) + fused attention logits
//   3. agg: ONE BLOCK (512 thr) PER GRAPH, DENSE MFMA FORM:
//      adjacency bitmask (LDS) -> dense masked logits + row softmax -> p bf16
//      [112][136] -> mfma_f32_16x16x32_bf16 against h^T bf16 [128][136]
//      (zero-padded cols 100..135!) -> 1/z scale, head-mean, bias(, relu)
//   4. preds = B @ Wc + bc ; y passthrough
// ---------------------------------------------------------------------------

#define NPG 100    // nodes per graph (fixed by problem)
#define CAP 2560   // bucket capacity per graph (mean 1700, +21 sigma)
#define EPB 4096   // edges per bucket-build block
#define SPAD 136   // h^T row stride (bf16): 272 B -> 16B-aligned, 2-way banks
#define PPAD 136   // p row stride (bf16): 272 B -> 16B-aligned, 2-way banks

typedef __attribute__((ext_vector_type(8))) short bf16x8;
typedef __attribute__((ext_vector_type(4))) float f32x4;

__device__ __forceinline__ float lrelu(float x) { return x > 0.f ? x : 0.2f * x; }

__device__ __forceinline__ unsigned short f2bf(float f) {
    unsigned int u = __float_as_uint(f);
    return (unsigned short)((u + 0x7FFF + ((u >> 16) & 1)) >> 16);  // RNE
}

// Two-level bucketing: per-block LDS histogram over graphs, one global
// atomicAdd per (block,graph), then scatter staged edges to reserved ranges.
__global__ __launch_bounds__(1024) void bucket2_kernel(const int* __restrict__ src,
                                                       const int* __restrict__ dst,
                                                       int* gcnt,
                                                       unsigned short* __restrict__ bucket,
                                                       int e) {
    __shared__ int hist[512];
    __shared__ int base[512];
    __shared__ unsigned int staged[EPB];
    int tid = threadIdx.x;
    int e0 = blockIdx.x * EPB;
    int cnt = min(EPB, e - e0);

    for (int i = tid; i < 512; i += 1024) hist[i] = 0;
    __syncthreads();

    for (int i = tid; i < cnt; i += 1024) {
        int d = dst[e0 + i];
        int s = src[e0 + i];
        int g = d / NPG;
        int dloc = d - g * NPG;
        int sloc = s - g * NPG;
        staged[i] = ((unsigned)g << 16) | ((unsigned)dloc << 8) | (unsigned)sloc;
        atomicAdd(&hist[g], 1);
    }
    __syncthreads();

    if (tid < 512) {
        int h = hist[tid];
        base[tid] = h ? atomicAdd(&gcnt[tid], h) : 0;
        hist[tid] = 0;   // reuse as local cursor
    }
    __syncthreads();

    for (int i = tid; i < cnt; i += 1024) {
        unsigned v = staged[i];
        int g = v >> 16;
        int pos = base[g] + atomicAdd(&hist[g], 1);
        if (pos < CAP)
            bucket[(size_t)g * CAP + pos] = (unsigned short)(v & 0xFFFFu);
    }
}

// X [n,K] @ W [K,128] -> H [n,128], fused attention logits.
template <int K>
__global__ __launch_bounds__(256) void gemm_nodes(const float* __restrict__ X,
                                                  const float* __restrict__ W,
                                                  const float* __restrict__ a_src,
                                                  const float* __restrict__ a_dst,
                                                  float* __restrict__ H,
                                                  float* __restrict__ als,
                                                  float* __restrict__ ald, int n) {
    constexpr int KC = 32;
    __shared__ float sX[64][KC + 1];
    __shared__ float sW[KC][132];
    int tid = threadIdx.x;
    int row0 = blockIdx.x * 64;
    int rg = tid >> 4;
    int cg = tid & 15;
    int r0 = rg * 4;
    int c0 = cg * 8;
    float acc[4][8];
#pragma unroll
    for (int i = 0; i < 4; ++i)
#pragma unroll
        for (int j = 0; j < 8; ++j) acc[i][j] = 0.f;

    for (int kc = 0; kc < K; kc += KC) {
        __syncthreads();
#pragma unroll
        for (int it = 0; it < 2; ++it) {
            int idx = tid + it * 256;
            int r = idx >> 3;
            int k4 = (idx & 7) * 4;
            int gr = row0 + r;
            float4 v = (gr < n) ? *reinterpret_cast<const float4*>(&X[(size_t)gr * K + kc + k4])
                                : make_float4(0.f, 0.f, 0.f, 0.f);
            sX[r][k4 + 0] = v.x; sX[r][k4 + 1] = v.y;
            sX[r][k4 + 2] = v.z; sX[r][k4 + 3] = v.w;
        }
#pragma unroll
        for (int it = 0; it < 4; ++it) {
            int idx = tid + it * 256;
            int kk = idx >> 5;
            int c4 = (idx & 31) * 4;
            *reinterpret_cast<float4*>(&sW[kk][c4]) =
                *reinterpret_cast<const float4*>(&W[(size_t)(kc + kk) * 128 + c4]);
        }
        __syncthreads();
#pragma unroll
        for (int k = 0; k < KC; ++k) {
            float x0 = sX[r0 + 0][k];
            float x1 = sX[r0 + 1][k];
            float x2 = sX[r0 + 2][k];
            float x3 = sX[r0 + 3][k];
            float4 w0 = *reinterpret_cast<const float4*>(&sW[k][c0]);
            float4 w1 = *reinterpret_cast<const float4*>(&sW[k][c0 + 4]);
            acc[0][0] += x0 * w0.x; acc[0][1] += x0 * w0.y; acc[0][2] += x0 * w0.z; acc[0][3] += x0 * w0.w;
            acc[0][4] += x0 * w1.x; acc[0][5] += x0 * w1.y; acc[0][6] += x0 * w1.z; acc[0][7] += x0 * w1.w;
            acc[1][0] += x1 * w0.x; acc[1][1] += x1 * w0.y; acc[1][2] += x1 * w0.z; acc[1][3] += x1 * w0.w;
            acc[1][4] += x1 * w1.x; acc[1][5] += x1 * w1.y; acc[1][6] += x1 * w1.z; acc[1][7] += x1 * w1.w;
            acc[2][0] += x2 * w0.x; acc[2][1] += x2 * w0.y; acc[2][2] += x2 * w0.z; acc[2][3] += x2 * w0.w;
            acc[2][4] += x2 * w1.x; acc[2][5] += x2 * w1.y; acc[2][6] += x2 * w1.z; acc[2][7] += x2 * w1.w;
            acc[3][0] += x3 * w0.x; acc[3][1] += x3 * w0.y; acc[3][2] += x3 * w0.z; acc[3][3] += x3 * w0.w;
            acc[3][4] += x3 * w1.x; acc[3][5] += x3 * w1.y; acc[3][6] += x3 * w1.z; acc[3][7] += x3 * w1.w;
        }
    }

#pragma unroll
    for (int i = 0; i < 4; ++i) {
        int gr = row0 + r0 + i;
        if (gr < n) {
            float4* o = reinterpret_cast<float4*>(&H[(size_t)gr * 128 + c0]);
            o[0] = make_float4(acc[i][0], acc[i][1], acc[i][2], acc[i][3]);
            o[1] = make_float4(acc[i][4], acc[i][5], acc[i][6], acc[i][7]);
        }
    }

    float ps[4], pd[4];
#pragma unroll
    for (int i = 0; i < 4; ++i) {
        float s = 0.f, d = 0.f;
#pragma unroll
        for (int j = 0; j < 8; ++j) {
            float av = acc[i][j];
            s += av * a_src[c0 + j];
            d += av * a_dst[c0 + j];
        }
        ps[i] = s; pd[i] = d;
    }
#pragma unroll
    for (int off = 1; off <= 4; off <<= 1) {
#pragma unroll
        for (int i = 0; i < 4; ++i) {
            ps[i] += __shfl_xor(ps[i], off);
            pd[i] += __shfl_xor(pd[i], off);
        }
    }
    if ((cg & 7) == 0) {
        int head = cg >> 3;
#pragma unroll
        for (int i = 0; i < 4; ++i) {
            int gr = row0 + r0 + i;
            if (gr < n) {
                als[gr * 2 + head] = ps[i];
                ald[gr * 2 + head] = pd[i];
            }
        }
    }
}

// One block (512 threads = 8 waves) per graph. Dense MFMA aggregation:
// adjacency bitmask -> masked dense softmax (p bf16) -> p @ h^T via
// mfma_f32_16x16x32_bf16 -> 1/z scale, head mean, bias, optional relu.
template <bool RELU>
__global__ __launch_bounds__(512) void agg_mfma(const float* __restrict__ Hf,
                                                const float* __restrict__ als,
                                                const float* __restrict__ ald,
                                                const int* __restrict__ gcnt,
                                                const unsigned short* __restrict__ bucket,
                                                const float* __restrict__ bias,
                                                float* __restrict__ out, int n) {
    __shared__ alignas(16) unsigned short sHT[128][SPAD];  // h^T bf16: [chan][node]
    __shared__ alignas(16) unsigned short sP[112][PPAD];   // p bf16 (current head)
    __shared__ unsigned int smask[NPG][4];      // adjacency bits: [dst][src/32]
    __shared__ float sAs[NPG * 2];
    __shared__ float sAd[NPG * 2];
    __shared__ float sRZ[112];                  // 1/z per dst (current head)

    int g = blockIdx.x;
    int gbase = g * NPG;
    int tid = threadIdx.x;
    int lane = tid & 63, wave = tid >> 6;
    int cnt = min(gcnt[g], CAP);

    // zero mask
    for (int i = tid; i < NPG * 4; i += 512) ((unsigned*)smask)[i] = 0;
    // zero sHT pad columns 100..135 (k-contraction reads cols 0..127; the
    // pad MUST be finite or 0*garbage => NaN poisons every output row)
    for (int i = tid; i < 128 * 18; i += 512) {
        int r = i / 18, c = 100 + (i % 18) * 2;
        *reinterpret_cast<unsigned int*>(&sHT[r][c]) = 0u;
    }
    // stage h -> h^T bf16 (transpose-convert)
    for (int i = tid; i < NPG * 32; i += 512) {
        int s = i >> 5, c4 = (i & 31) * 4;
        float4 v = *reinterpret_cast<const float4*>(&Hf[(size_t)(gbase + s) * 128 + c4]);
        sHT[c4 + 0][s] = f2bf(v.x);
        sHT[c4 + 1][s] = f2bf(v.y);
        sHT[c4 + 2][s] = f2bf(v.z);
        sHT[c4 + 3][s] = f2bf(v.w);
    }
    for (int i = tid; i < NPG * 2; i += 512) {
        sAs[i] = als[gbase * 2 + i];
        sAd[i] = ald[gbase * 2 + i];
    }
    __syncthreads();

    // adjacency bitmask from bucket
    for (int i = tid; i < cnt; i += 512) {
        unsigned v = bucket[(size_t)g * CAP + i];
        atomicOr(&smask[v >> 8][(v & 255) >> 5], 1u << (v & 31));
    }
    __syncthreads();

    f32x4 res[4];
#pragma unroll
    for (int i = 0; i < 4; ++i) res[i] = (f32x4){0.f, 0.f, 0.f, 0.f};

    for (int head = 0; head < 2; ++head) {
        // ---- dense masked softmax: one wave per dst row, lanes cover s ----
        for (int d = wave; d < NPG; d += 8) {
            float adh = sAd[d * 2 + head];
            unsigned w0 = smask[d][lane >> 5];
            unsigned w1 = smask[d][2 + (lane >> 5)];
            int s2 = lane + 64;
            int si2 = (s2 < NPG) ? s2 : 0;
            bool b1 = (w0 >> (lane & 31)) & 1;
            bool b2 = (s2 < NPG) && ((w1 >> (lane & 31)) & 1);
            float e1 = b1 ? lrelu(sAs[lane * 2 + head] + adh) : -INFINITY;
            float e2 = b2 ? lrelu(sAs[si2 * 2 + head] + adh) : -INFINITY;
            float m = fmaxf(e1, e2);
            for (int off = 32; off; off >>= 1) m = fmaxf(m, __shfl_xor(m, off));
            float p1 = __expf(e1 - m);   // exp(-inf - m) = 0
            float p2 = __expf(e2 - m);
            float z = p1 + p2;
            for (int off = 32; off; off >>= 1) z += __shfl_xor(z, off);
            sP[d][lane] = f2bf(p1);
            sP[d][s2] = f2bf(p2);
            if (lane == 0) sRZ[d] = 1.f / z;
        }
        __syncthreads();

        // ---- MFMA: D[112x64] = P[112x128] x hT_head[128x64] ----
        // tiles t = mt*4+nt, t in [0,28); wave handles t = wave + 8i.
#pragma unroll
        for (int i = 0; i < 4; ++i) {
            int t = wave + 8 * i;
            if (t < 28) {
                int mt = t >> 2, nt = t & 3;
                int arow = mt * 16 + (lane & 15);
                int brow = head * 64 + nt * 16 + (lane & 15);
                int kofs = (lane >> 4) * 8;
                f32x4 acc = (f32x4){0.f, 0.f, 0.f, 0.f};
#pragma unroll
                for (int ks = 0; ks < 4; ++ks) {
                    bf16x8 a = *reinterpret_cast<const bf16x8*>(&sP[arow][ks * 32 + kofs]);
                    bf16x8 b = *reinterpret_cast<const bf16x8*>(&sHT[brow][ks * 32 + kofs]);
                    acc = __builtin_amdgcn_mfma_f32_16x16x32_bf16(a, b, acc, 0, 0, 0);
                }
                int dbase = mt * 16 + (lane >> 4) * 4;
#pragma unroll
                for (int r = 0; r < 4; ++r)
                    res[i][r] += acc[r] * sRZ[dbase + r];
            }
        }
        __syncthreads();   // before next head overwrites sP/sRZ
    }

    // ---- epilogue: head mean + bias (+ relu), store ----
#pragma unroll
    for (int i = 0; i < 4; ++i) {
        int t = wave + 8 * i;
        if (t < 28) {
            int mt = t >> 2, nt = t & 3;
            int col = nt * 16 + (lane & 15);
            float bv = bias[col];
#pragma unroll
            for (int r = 0; r < 4; ++r) {
                int d = mt * 16 + (lane >> 4) * 4 + r;
                if (d < NPG) {
                    float v = 0.5f * res[i][r] + bv;
                    if (RELU) v = fmaxf(v, 0.f);
                    out[(size_t)(gbase + d) * 64 + col] = v;
                }
            }
        }
    }
}

// preds = Hf [n,64] @ Wc [64,10] + bc; one thread per node.
__global__ __launch_bounds__(256) void cls_kernel(const float* __restrict__ Hf,
                                                  const float* __restrict__ Wc,
                                                  const float* __restrict__ bc,
                                                  float* __restrict__ out, int n) {
    __shared__ float sW[640];
    __shared__ float sb[10];
    int tid = threadIdx.x;
    for (int i = tid; i < 640; i += 256) sW[i] = Wc[i];
    if (tid < 10) sb[tid] = bc[tid];
    __syncthreads();
    int node = blockIdx.x * 256 + tid;
    if (node >= n) return;
    float acc[10];
#pragma unroll
    for (int j = 0; j < 10; ++j) acc[j] = sb[j];
    for (int k = 0; k < 64; k += 4) {
        float4 h4 = *reinterpret_cast<const float4*>(&Hf[(size_t)node * 64 + k]);
#pragma unroll
        for (int j = 0; j < 10; ++j) {
            acc[j] += h4.x * sW[(k + 0) * 10 + j];
            acc[j] += h4.y * sW[(k + 1) * 10 + j];
            acc[j] += h4.z * sW[(k + 2) * 10 + j];
            acc[j] += h4.w * sW[(k + 3) * 10 + j];
        }
    }
#pragma unroll
    for (int j = 0; j < 10; ++j) out[(size_t)node * 10 + j] = acc[j];
}

__global__ void ycopy_kernel(const int* __restrict__ y, float* __restrict__ out, int n) {
    int i = blockIdx.x * 256 + threadIdx.x;
    if (i < n) out[i] = (float)y[i];
}

extern "C" void kernel_launch(void* const* d_in, const int* in_sizes, int n_in,
                              void* d_out, int out_size, void* d_ws, size_t ws_size,
                              hipStream_t stream) {
    const float* x   = (const float*)d_in[0];
    const int*   ei  = (const int*)d_in[1];
    const int*   y   = (const int*)d_in[3];
    const float* W1  = (const float*)d_in[4];
    const float* as1 = (const float*)d_in[5];
    const float* ad1 = (const float*)d_in[6];
    const float* b1  = (const float*)d_in[7];
    const float* W2  = (const float*)d_in[8];
    const float* as2 = (const float*)d_in[9];
    const float* ad2 = (const float*)d_in[10];
    const float* b2  = (const float*)d_in[11];
    const float* Wc  = (const float*)d_in[12];
    const float* bc  = (const float*)d_in[13];

    int n = in_sizes[0] / 128;   // 50000
    int e = in_sizes[1] / 2;     // 850000
    int G = n / NPG;             // 500 graphs
    const int* src = ei;
    const int* dst = ei + e;

    char* ws = (char*)d_ws;
    size_t off = 0;
    auto alloc = [&](size_t bytes) -> void* {
        void* p = ws + off;
        off = (off + bytes + 255) & ~size_t(255);
        return p;
    };
    float* A    = (float*)alloc((size_t)n * 128 * 4);
    float* B    = (float*)alloc((size_t)n * 64 * 4);
    float* als  = (float*)alloc((size_t)n * 2 * 4);
    float* ald  = (float*)alloc((size_t)n * 2 * 4);
    int*   gcnt = (int*)alloc((size_t)G * 4);
    unsigned short* bucket = (unsigned short*)alloc((size_t)G * CAP * 2);

    float* preds = (float*)d_out;
    float* yout  = preds + (size_t)n * 10;

    int nb64 = (n + 63) / 64;
    int nb256 = (n + 255) / 256;
    int bb = (e + EPB - 1) / EPB;

    // bucket edges by graph (rebuilt every call: no cross-call state)
    hipMemsetAsync(gcnt, 0, (size_t)G * 4, stream);
    bucket2_kernel<<<bb, 1024, 0, stream>>>(src, dst, gcnt, bucket, e);

    // layer 1
    gemm_nodes<128><<<nb64, 256, 0, stream>>>(x, W1, as1, ad1, A, als, ald, n);
    agg_mfma<true><<<G, 512, 0, stream>>>(A, als, ald, gcnt, bucket, b1, B, n);

    // layer 2
    gemm_nodes<64><<<nb64, 256, 0, stream>>>(B, W2, as2, ad2, A, als, ald, n);
    agg_mfma<false><<<G, 512, 0, stream>>>(A, als, ald, gcnt, bucket, b2, B, n);

    // classifier + y passthrough
    cls_kernel<<<nb256, 256, 0, stream>>>(B, Wc, bc, preds, n);
    ycopy_kernel<<<nb256, 256, 0, stream>>>(y, yout, n);
}

// Round 9
// 126.140 us; speedup vs baseline: 3.5248x; 1.1703x over previous
//
#include <hip/hip_runtime.h>
#include <math.h>

// ---------------------------------------------------------------------------
// GAT node classifier: 2x GATConv(H=2, concat=False/head-mean) + Linear.
//   0. zero gcnt (custom kernel; hipMemsetAsync's fillBuffer cost 43us!)
//   1. bucket edges by graph (two-level LDS-histogram scatter, packed ushort)
//   2. prep: xb = bf16(x); W1T/W2T = bf16 transposed weights (k-contiguous)
//   3. gemm_mfma: H = X @ W via mfma_f32_16x16x32_bf16 (64 rows/block,
//      8 col-tiles/wave) + fused attention logits from f32 accs; H out bf16
//   4. agg_mfma: per-graph dense form with 4-BIT EDGE MULTIPLICITY (the
//      reference's segment_sum counts duplicate edges; a 0/1 bitmask is
//      wrong by ~0.066 absmax) -> masked softmax p=mult*exp(e-m) -> P@hT
//      MFMA -> 1/z, head-mean, bias(, relu)
//   5. preds = B @ Wc + bc ; y passthrough
// ---------------------------------------------------------------------------

#define NPG 100    // nodes per graph (fixed by problem)
#define CAP 2560   // bucket capacity per graph (mean 1700, +21 sigma)
#define EPB 4096   // edges per bucket-build block
#define PPAD 136   // bf16 row stride for MFMA LDS tiles: 272 B (16B-aligned,
                   // bank stride 68 dwords -> 2-way aliasing = free)

typedef __attribute__((ext_vector_type(8))) short bf16x8;
typedef __attribute__((ext_vector_type(4))) float f32x4;

__device__ __forceinline__ float lrelu(float x) { return x > 0.f ? x : 0.2f * x; }

__device__ __forceinline__ unsigned short f2bf(float f) {
    unsigned int u = __float_as_uint(f);
    return (unsigned short)((u + 0x7FFF + ((u >> 16) & 1)) >> 16);  // RNE
}

__global__ void zero_gcnt(int* gcnt, int g) {
    int i = threadIdx.x;
    if (i < g) gcnt[i] = 0;
}

// Two-level bucketing: per-block LDS histogram over graphs, one global
// atomicAdd per (block,graph), then scatter staged edges to reserved ranges.
__global__ __launch_bounds__(1024) void bucket2_kernel(const int* __restrict__ src,
                                                       const int* __restrict__ dst,
                                                       int* gcnt,
                                                       unsigned short* __restrict__ bucket,
                                                       int e) {
    __shared__ int hist[512];
    __shared__ int base[512];
    __shared__ unsigned int staged[EPB];
    int tid = threadIdx.x;
    int e0 = blockIdx.x * EPB;
    int cnt = min(EPB, e - e0);

    for (int i = tid; i < 512; i += 1024) hist[i] = 0;
    __syncthreads();

    for (int i = tid; i < cnt; i += 1024) {
        int d = dst[e0 + i];
        int s = src[e0 + i];
        int g = d / NPG;
        int dloc = d - g * NPG;
        int sloc = s - g * NPG;
        staged[i] = ((unsigned)g << 16) | ((unsigned)dloc << 8) | (unsigned)sloc;
        atomicAdd(&hist[g], 1);
    }
    __syncthreads();

    if (tid < 512) {
        int h = hist[tid];
        base[tid] = h ? atomicAdd(&gcnt[tid], h) : 0;
        hist[tid] = 0;   // reuse as local cursor
    }
    __syncthreads();

    for (int i = tid; i < cnt; i += 1024) {
        unsigned v = staged[i];
        int g = v >> 16;
        int pos = base[g] + atomicAdd(&hist[g], 1);
        if (pos < CAP)
            bucket[(size_t)g * CAP + pos] = (unsigned short)(v & 0xFFFFu);
    }
}

// x f32 -> bf16, vector form (total4 = n*128/4)
__global__ __launch_bounds__(256) void convert_x(const float* __restrict__ x,
                                                 unsigned short* __restrict__ xb,
                                                 int total4) {
    for (int i = blockIdx.x * 256 + threadIdx.x; i < total4; i += gridDim.x * 256) {
        float4 v = reinterpret_cast<const float4*>(x)[i];
        ushort4 b;
        b.x = f2bf(v.x); b.y = f2bf(v.y); b.z = f2bf(v.z); b.w = f2bf(v.w);
        reinterpret_cast<ushort4*>(xb)[i] = b;
    }
}

// W1 [128][128], W2 [64][128] f32 -> W1T [c][k=128], W2T [c][k=64] bf16
__global__ __launch_bounds__(256) void convert_w(const float* __restrict__ W1,
                                                 const float* __restrict__ W2,
                                                 unsigned short* __restrict__ W1T,
                                                 unsigned short* __restrict__ W2T) {
    int stride = gridDim.x * 256;
    for (int i = blockIdx.x * 256 + threadIdx.x; i < 128 * 128; i += stride) {
        int k = i >> 7, c = i & 127;
        W1T[c * 128 + k] = f2bf(W1[i]);
    }
    for (int i = blockIdx.x * 256 + threadIdx.x; i < 64 * 128; i += stride) {
        int k = i >> 7, c = i & 127;
        W2T[c * 64 + k] = f2bf(W2[i]);
    }
}

// H = Xb @ W (bf16 MFMA), fused attention logits. 64 rows/block, 256 thr
// (4 waves); each wave: 16 rows x 128 cols = 8 16x16 tiles, K staged whole.
// Fragment pattern verified by round-8 agg_mfma (passed on-device):
//   a: sX[row16 + (lane&15)][ks*32 + (lane>>4)*8], b: sW[col-tile likewise],
//   D: col = lane&15, row = (lane>>4)*4 + j.
template <int K>
__global__ __launch_bounds__(256) void gemm_mfma(const unsigned short* __restrict__ Xb,
                                                 const unsigned short* __restrict__ WT,
                                                 const float* __restrict__ a_src,
                                                 const float* __restrict__ a_dst,
                                                 unsigned short* __restrict__ Hb,
                                                 float* __restrict__ als,
                                                 float* __restrict__ ald, int n) {
    constexpr int SX = K + 8;   // 272 B (K=128) / 144 B (K=64) row stride
    __shared__ alignas(16) unsigned short sX[64][SX];
    __shared__ alignas(16) unsigned short sW[128][SX];
    int tid = threadIdx.x, lane = tid & 63, wave = tid >> 6;
    int row0 = blockIdx.x * 64;

    constexpr int KCH = K / 8;   // 16B chunks per row
    for (int i = tid; i < 64 * KCH; i += 256) {
        int r = i / KCH, kc = (i % KCH) * 8;
        int gr = row0 + r;
        float4 v = (gr < n) ? *reinterpret_cast<const float4*>(&Xb[(size_t)gr * K + kc])
                            : make_float4(0.f, 0.f, 0.f, 0.f);
        *reinterpret_cast<float4*>(&sX[r][kc]) = v;
    }
    for (int i = tid; i < 128 * KCH; i += 256) {
        int c = i / KCH, kc = (i % KCH) * 8;
        *reinterpret_cast<float4*>(&sW[c][kc]) =
            *reinterpret_cast<const float4*>(&WT[c * K + kc]);
    }
    __syncthreads();

    int fr = lane & 15, fk = (lane >> 4) * 8;
    f32x4 acc[8];
#pragma unroll
    for (int t = 0; t < 8; ++t) acc[t] = (f32x4){0.f, 0.f, 0.f, 0.f};

#pragma unroll
    for (int ks = 0; ks < K / 32; ++ks) {
        bf16x8 a = *reinterpret_cast<const bf16x8*>(&sX[wave * 16 + fr][ks * 32 + fk]);
#pragma unroll
        for (int t = 0; t < 8; ++t) {
            bf16x8 b = *reinterpret_cast<const bf16x8*>(&sW[t * 16 + fr][ks * 32 + fk]);
            acc[t] = __builtin_amdgcn_mfma_f32_16x16x32_bf16(a, b, acc[t], 0, 0, 0);
        }
    }

    // write Hb (bf16) + attention-logit partials from f32 accs
    int rb = wave * 16 + (lane >> 4) * 4;
    float ps0[4] = {0, 0, 0, 0}, ps1[4] = {0, 0, 0, 0};
    float pd0[4] = {0, 0, 0, 0}, pd1[4] = {0, 0, 0, 0};
#pragma unroll
    for (int t = 0; t < 8; ++t) {
        int col = t * 16 + fr;
        float as_ = a_src[col], ad_ = a_dst[col];
#pragma unroll
        for (int j = 0; j < 4; ++j) {
            float v = acc[t][j];
            int gr = row0 + rb + j;
            if (gr < n) Hb[(size_t)gr * 128 + col] = f2bf(v);
            if (t < 4) { ps0[j] += v * as_; pd0[j] += v * ad_; }
            else       { ps1[j] += v * as_; pd1[j] += v * ad_; }
        }
    }
#pragma unroll
    for (int off = 1; off <= 8; off <<= 1) {
#pragma unroll
        for (int j = 0; j < 4; ++j) {
            ps0[j] += __shfl_xor(ps0[j], off);
            ps1[j] += __shfl_xor(ps1[j], off);
            pd0[j] += __shfl_xor(pd0[j], off);
            pd1[j] += __shfl_xor(pd1[j], off);
        }
    }
    if (fr == 0) {
#pragma unroll
        for (int j = 0; j < 4; ++j) {
            int gr = row0 + rb + j;
            if (gr < n) {
                als[gr * 2 + 0] = ps0[j];
                als[gr * 2 + 1] = ps1[j];
                ald[gr * 2 + 0] = pd0[j];
                ald[gr * 2 + 1] = pd1[j];
            }
        }
    }
}

// One block (512 threads = 8 waves) per graph. Dense MFMA aggregation with
// 4-bit edge multiplicity: p = mult * exp(e - m). OBF16 selects bf16 output
// (feeds layer-2 gemm) vs f32 (feeds classifier).
template <bool RELU, bool OBF16>
__global__ __launch_bounds__(512) void agg_mfma(const unsigned short* __restrict__ Hb,
                                                const float* __restrict__ als,
                                                const float* __restrict__ ald,
                                                const int* __restrict__ gcnt,
                                                const unsigned short* __restrict__ bucket,
                                                const float* __restrict__ bias,
                                                void* __restrict__ outv, int n) {
    __shared__ alignas(16) unsigned short sHT[128][PPAD];  // h^T bf16 [chan][node]
    __shared__ alignas(16) unsigned short sP[112][PPAD];   // p bf16 (current head)
    __shared__ unsigned int scnt[NPG][16];   // 4-bit multiplicities, s in [0,128)
    __shared__ float sAs[NPG * 2];
    __shared__ float sAd[NPG * 2];
    __shared__ float sRZ[112];               // 1/z per dst (current head)

    int g = blockIdx.x;
    int gbase = g * NPG;
    int tid = threadIdx.x;
    int lane = tid & 63, wave = tid >> 6;
    int cnt = min(gcnt[g], CAP);

    for (int i = tid; i < NPG * 16; i += 512) ((unsigned*)scnt)[i] = 0;
    // zero sHT pad cols 100..135 (k-contraction reads 0..127; 0*garbage=NaN)
    for (int i = tid; i < 128 * 18; i += 512) {
        int r = i / 18, c = 100 + (i % 18) * 2;
        *reinterpret_cast<unsigned int*>(&sHT[r][c]) = 0u;
    }
    // stage h^T: lanes take consecutive nodes s for one channel-group c8
    // (2-way LDS write banks; reads hit the Hb tile in L2)
    for (int i = tid; i < 16 * 128; i += 512) {
        int s = i & 127, c8 = (i >> 7) * 8;
        if (s < NPG) {
            float4 raw = *reinterpret_cast<const float4*>(&Hb[(size_t)(gbase + s) * 128 + c8]);
            const unsigned short* u = reinterpret_cast<const unsigned short*>(&raw);
#pragma unroll
            for (int j = 0; j < 8; ++j) sHT[c8 + j][s] = u[j];
        }
    }
    for (int i = tid; i < NPG * 2; i += 512) {
        sAs[i] = als[gbase * 2 + i];
        sAd[i] = ald[gbase * 2 + i];
    }
    __syncthreads();

    // edge multiplicity (duplicates matter: reference sums per-edge!)
    for (int i = tid; i < cnt; i += 512) {
        unsigned v = bucket[(size_t)g * CAP + i];
        atomicAdd(&scnt[v >> 8][(v & 255) >> 3], 1u << ((v & 7) * 4));
    }
    __syncthreads();

    f32x4 res[4];
#pragma unroll
    for (int i = 0; i < 4; ++i) res[i] = (f32x4){0.f, 0.f, 0.f, 0.f};

    for (int head = 0; head < 2; ++head) {
        // ---- dense masked softmax: one wave per dst row, lanes cover s ----
        for (int d = wave; d < NPG; d += 8) {
            float adh = sAd[d * 2 + head];
            int s2 = lane + 64;
            unsigned m1 = (scnt[d][lane >> 3] >> ((lane & 7) * 4)) & 15u;
            unsigned m2 = (s2 < NPG) ? ((scnt[d][s2 >> 3] >> ((s2 & 7) * 4)) & 15u) : 0u;
            int si2 = (s2 < NPG) ? s2 : 0;
            float e1 = m1 ? lrelu(sAs[lane * 2 + head] + adh) : -INFINITY;
            float e2 = m2 ? lrelu(sAs[si2 * 2 + head] + adh) : -INFINITY;
            float mx = fmaxf(e1, e2);
            for (int off = 32; off; off >>= 1) mx = fmaxf(mx, __shfl_xor(mx, off));
            float p1 = (float)m1 * __expf(e1 - mx);   // 0 * exp(-inf) = 0
            float p2 = (float)m2 * __expf(e2 - mx);
            float z = p1 + p2;
            for (int off = 32; off; off >>= 1) z += __shfl_xor(z, off);
            sP[d][lane] = f2bf(p1);
            sP[d][s2] = f2bf(p2);
            if (lane == 0) sRZ[d] = 1.f / z;
        }
        __syncthreads();

        // ---- MFMA: D[112x64] = P[112x128] x hT_head[128x64] ----
#pragma unroll
        for (int i = 0; i < 4; ++i) {
            int t = wave + 8 * i;
            if (t < 28) {
                int mt = t >> 2, nt = t & 3;
                int arow = mt * 16 + (lane & 15);
                int brow = head * 64 + nt * 16 + (lane & 15);
                int kofs = (lane >> 4) * 8;
                f32x4 acc = (f32x4){0.f, 0.f, 0.f, 0.f};
#pragma unroll
                for (int ks = 0; ks < 4; ++ks) {
                    bf16x8 a = *reinterpret_cast<const bf16x8*>(&sP[arow][ks * 32 + kofs]);
                    bf16x8 b = *reinterpret_cast<const bf16x8*>(&sHT[brow][ks * 32 + kofs]);
                    acc = __builtin_amdgcn_mfma_f32_16x16x32_bf16(a, b, acc, 0, 0, 0);
                }
                int dbase = mt * 16 + (lane >> 4) * 4;
#pragma unroll
                for (int r = 0; r < 4; ++r)
                    res[i][r] += acc[r] * sRZ[dbase + r];
            }
        }
        __syncthreads();   // before next head overwrites sP/sRZ
    }

    // ---- epilogue: head mean + bias (+ relu), store ----
#pragma unroll
    for (int i = 0; i < 4; ++i) {
        int t = wave + 8 * i;
        if (t < 28) {
            int mt = t >> 2, nt = t & 3;
            int col = nt * 16 + (lane & 15);
            float bv = bias[col];
#pragma unroll
            for (int r = 0; r < 4; ++r) {
                int d = mt * 16 + (lane >> 4) * 4 + r;
                if (d < NPG) {
                    float v = 0.5f * res[i][r] + bv;
                    if (RELU) v = fmaxf(v, 0.f);
                    size_t idx = (size_t)(gbase + d) * 64 + col;
                    if (OBF16) ((unsigned short*)outv)[idx] = f2bf(v);
                    else       ((float*)outv)[idx] = v;
                }
            }
        }
    }
}

// preds = Hf [n,64] @ Wc [64,10] + bc; one thread per node.
__global__ __launch_bounds__(256) void cls_kernel(const float* __restrict__ Hf,
                                                  const float* __restrict__ Wc,
                                                  const float* __restrict__ bc,
                                                  float* __restrict__ out, int n) {
    __shared__ float sW[640];
    __shared__ float sb[10];
    int tid = threadIdx.x;
    for (int i = tid; i < 640; i += 256) sW[i] = Wc[i];
    if (tid < 10) sb[tid] = bc[tid];
    __syncthreads();
    int node = blockIdx.x * 256 + tid;
    if (node >= n) return;
    float acc[10];
#pragma unroll
    for (int j = 0; j < 10; ++j) acc[j] = sb[j];
    for (int k = 0; k < 64; k += 4) {
        float4 h4 = *reinterpret_cast<const float4*>(&Hf[(size_t)node * 64 + k]);
#pragma unroll
        for (int j = 0; j < 10; ++j) {
            acc[j] += h4.x * sW[(k + 0) * 10 + j];
            acc[j] += h4.y * sW[(k + 1) * 10 + j];
            acc[j] += h4.z * sW[(k + 2) * 10 + j];
            acc[j] += h4.w * sW[(k + 3) * 10 + j];
        }
    }
#pragma unroll
    for (int j = 0; j < 10; ++j) out[(size_t)node * 10 + j] = acc[j];
}

__global__ void ycopy_kernel(const int* __restrict__ y, float* __restrict__ out, int n) {
    int i = blockIdx.x * 256 + threadIdx.x;
    if (i < n) out[i] = (float)y[i];
}

extern "C" void kernel_launch(void* const* d_in, const int* in_sizes, int n_in,
                              void* d_out, int out_size, void* d_ws, size_t ws_size,
                              hipStream_t stream) {
    const float* x   = (const float*)d_in[0];
    const int*   ei  = (const int*)d_in[1];
    const int*   y   = (const int*)d_in[3];
    const float* W1  = (const float*)d_in[4];
    const float* as1 = (const float*)d_in[5];
    const float* ad1 = (const float*)d_in[6];
    const float* b1  = (const float*)d_in[7];
    const float* W2  = (const float*)d_in[8];
    const float* as2 = (const float*)d_in[9];
    const float* ad2 = (const float*)d_in[10];
    const float* b2  = (const float*)d_in[11];
    const float* Wc  = (const float*)d_in[12];
    const float* bc  = (const float*)d_in[13];

    int n = in_sizes[0] / 128;   // 50000
    int e = in_sizes[1] / 2;     // 850000
    int G = n / NPG;             // 500 graphs
    const int* src = ei;
    const int* dst = ei + e;

    char* ws = (char*)d_ws;
    size_t off = 0;
    auto alloc = [&](size_t bytes) -> void* {
        void* p = ws + off;
        off = (off + bytes + 255) & ~size_t(255);
        return p;
    };
    unsigned short* xb  = (unsigned short*)alloc((size_t)n * 128 * 2);  // bf16 x;
    float*          B2  = (float*)xb;  // aliased: xb dead after gemm1, B2 born at agg2
    unsigned short* Hb  = (unsigned short*)alloc((size_t)n * 128 * 2);  // bf16 h (both layers)
    unsigned short* Bb  = (unsigned short*)alloc((size_t)n * 64 * 2);   // bf16 layer-1 out
    float* als = (float*)alloc((size_t)n * 2 * 4);
    float* ald = (float*)alloc((size_t)n * 2 * 4);
    unsigned short* W1T = (unsigned short*)alloc((size_t)128 * 128 * 2);
    unsigned short* W2T = (unsigned short*)alloc((size_t)128 * 64 * 2);
    int* gcnt = (int*)alloc((size_t)G * 4);
    unsigned short* bucket = (unsigned short*)alloc((size_t)G * CAP * 2);

    float* preds = (float*)d_out;
    float* yout  = preds + (size_t)n * 10;

    int nb64 = (n + 63) / 64;
    int nb256 = (n + 255) / 256;
    int bb = (e + EPB - 1) / EPB;

    // CSR-free edge bucketing (rebuilt every call: no cross-call state)
    zero_gcnt<<<1, 512, 0, stream>>>(gcnt, G);
    bucket2_kernel<<<bb, 1024, 0, stream>>>(src, dst, gcnt, bucket, e);

    // bf16 prep
    convert_x<<<2048, 256, 0, stream>>>(x, xb, n * 128 / 4);
    convert_w<<<96, 256, 0, stream>>>(W1, W2, W1T, W2T);

    // layer 1
    gemm_mfma<128><<<nb64, 256, 0, stream>>>(xb, W1T, as1, ad1, Hb, als, ald, n);
    agg_mfma<true, true><<<G, 512, 0, stream>>>(Hb, als, ald, gcnt, bucket, b1, Bb, n);

    // layer 2
    gemm_mfma<64><<<nb64, 256, 0, stream>>>(Bb, W2T, as2, ad2, Hb, als, ald, n);
    agg_mfma<false, false><<<G, 512, 0, stream>>>(Hb, als, ald, gcnt, bucket, b2, B2, n);

    // classifier + y passthrough
    cls_kernel<<<nb256, 256, 0, stream>>>(B2, Wc, bc, preds, n);
    ycopy_kernel<<<nb256, 256, 0, stream>>>(y, yout, n);
}